// Round 9
// baseline (285.798 us; speedup 1.0000x reference)
//
#include <hip/hip_runtime.h>
#include <hip/hip_bf16.h>
#include <math.h>

#define NTOK 32768
#define HID  1024
#define NEXP 64
#define H4   256

typedef __attribute__((ext_vector_type(8)))  short bf16x8;
typedef __attribute__((ext_vector_type(8)))  unsigned short u16x8;
typedef __attribute__((ext_vector_type(16))) float f32x16;

static __device__ __forceinline__ ushort f2bf(float x) {
    unsigned u = __float_as_uint(x);
    unsigned r = (u + 0x7FFFu + ((u >> 16) & 1u)) >> 16;   // RNE
    return (ushort)r;
}

// RNE-cascade 3-way split: x = h + m + l + O(2^-27 |x|).
static __device__ __forceinline__ void split3r(float x, ushort &h, ushort &m, ushort &l) {
    h = f2bf(x);
    const float r1 = x - __uint_as_float(((unsigned)h) << 16);
    m = f2bf(r1);
    const float r2 = r1 - __uint_as_float(((unsigned)m) << 16);
    l = f2bf(r2);
}

// LDS hash for the X tile (proven rounds 2..8).
#define SWZ(row, us) ((us) ^ (((row) & 7) << 3))

// ---------------------------------------------------------------------------
// Kernel 0 (prep): weights -> 32x32x16 B-FRAGMENT-ORDER global layouts.
// B-operand mapping for v_mfma_f32_32x32x16_bf16: lane = h5*32 + (col&31)
// holds B[col][k = ks*... + h5*8 + i] (consistent extension of the proven
// 16x16x32 mapping where lane = quad*16 + l15, k = quad*8 + i).
//   W1f[p][tcj][ks][piece][lane][8] : p*16384 + tcj*2048 + ks*1024 + piece*512 + lane*8
//   RWf[p][tc ][ks][piece][lane][8] : p*6144  + tc*3072  + ks*1536 + piece*512 + lane*8
// ---------------------------------------------------------------------------
__global__ __launch_bounds__(256) void prep_kernel(
    const float* __restrict__ W1, const float* __restrict__ RW,
    ushort* __restrict__ W1f, ushort* __restrict__ RWf)
{
    if (blockIdx.x < 256) {
        const int id = blockIdx.x * 256 + threadIdx.x;
        const int c  = id >> 8;                      // 0..255 (w1 output col)
        const int k0 = (id & 255) * 4;               // 0..1020, multiple of 4
        const float4 v = *(const float4*)(W1 + (size_t)c * HID + k0);
        const int p  = k0 >> 5;
        const int ks = (k0 >> 4) & 1;
        const int h5 = (k0 >> 3) & 1;
        const int i0 = k0 & 7;                       // 0 or 4
        const int tcj = c >> 5, c31 = c & 31;
        const int lane = h5 * 32 + c31;
        const size_t base = (size_t)p * 16384 + tcj * 2048 + ks * 1024 + lane * 8 + i0;
        const float xs[4] = {v.x, v.y, v.z, v.w};
        ushort hv[4], lv[4];
#pragma unroll
        for (int q = 0; q < 4; q++) {
            const ushort h = f2bf(xs[q]);
            hv[q] = h;
            lv[q] = f2bf(xs[q] - __uint_as_float(((unsigned)h) << 16));
        }
        *(ushort4*)(W1f + base)       = make_ushort4(hv[0], hv[1], hv[2], hv[3]);
        *(ushort4*)(W1f + base + 512) = make_ushort4(lv[0], lv[1], lv[2], lv[3]);
    } else {
        const int e  = blockIdx.x - 256;             // expert, 0..63
        const int k0 = threadIdx.x * 4;              // 0..1020
        const float4 v = *(const float4*)(RW + (size_t)e * HID + k0);
        const int p  = k0 >> 5;
        const int ks = (k0 >> 4) & 1;
        const int h5 = (k0 >> 3) & 1;
        const int i0 = k0 & 7;
        const int tc = e >> 5, c31 = e & 31;
        const int lane = h5 * 32 + c31;
        const size_t base = (size_t)p * 6144 + tc * 3072 + ks * 1536 + lane * 8 + i0;
        const float xs[4] = {v.x, v.y, v.z, v.w};
        ushort h[4], m[4], l[4];
#pragma unroll
        for (int q = 0; q < 4; q++) split3r(xs[q], h[q], m[q], l[q]);
        *(ushort4*)(RWf + base)        = make_ushort4(h[0], h[1], h[2], h[3]);
        *(ushort4*)(RWf + base + 512)  = make_ushort4(m[0], m[1], m[2], m[3]);
        *(ushort4*)(RWf + base + 1024) = make_ushort4(l[0], l[1], l[2], l[3]);
    }
}

// ---------------------------------------------------------------------------
// Kernel 1 (v13): 32x32x16 MFMA — 2x arithmetic intensity per LDS byte.
// Round-8 diagnosis: MfmaUtil pinned 31-34% across 5 schedules; per-CU-panel
// pipe work = MFMA 2650 + LDS ~1800 + VALU ~1650 of ~7500 cyc; nothing
// saturated, 2 waves/SIMD can't overlap it. 32x32x16 halves A-LDS reads
// (96->48 KB/CU-panel), cuts MFMA cycles ~12% and instruction count 2x.
// Wave w: tr=w>>1 (32 tokens), tc=w&1. Logits: 1 32x32 tile, 6-product
// exact split; pred: 4 tiles, 3 products. W/RW same-iter global->VGPR
// (v12 showed dbuf negative); X reg-prefetch pipeline + counted fence kept.
// ---------------------------------------------------------------------------
template<int PH>
__device__ __forceinline__ void kstep(
    int p, int tr, int tc, int lane, int l31, int h5, int row, int kc,
    const float* __restrict__ xsrc,
    const ushort* __restrict__ RWf, const ushort* __restrict__ W1f,
    ushort (&Xh)[2][2048], ushort (&Xm)[2][2048], ushort (&Xl)[2][2048],
    float4 (&xp)[2][2],
    f32x16 &accL, f32x16 (&accP)[4])
{
    // 1. B loads for THIS panel (global->VGPR, L2-resident, issued first)
    const ushort* __restrict__ rwp = RWf + (size_t)p * 6144 + tc * 3072 + lane * 8;
    bf16x8 rwh[2], rwm[2], rwl[2];
#pragma unroll
    for (int ks = 0; ks < 2; ++ks) {
        rwh[ks] = *(const bf16x8*)(rwp + ks * 1536);
        rwm[ks] = *(const bf16x8*)(rwp + ks * 1536 + 512);
        rwl[ks] = *(const bf16x8*)(rwp + ks * 1536 + 1024);
    }
    const ushort* __restrict__ w1p = W1f + (size_t)p * 16384 + (tc * 4) * 2048 + lane * 8;
    bf16x8 bwh[2][4], bwl[2][4];
#pragma unroll
    for (int ks = 0; ks < 2; ++ks)
#pragma unroll
        for (int j = 0; j < 4; ++j) {
            bwh[ks][j] = *(const bf16x8*)(w1p + j * 2048 + ks * 1024);
            bwl[ks][j] = *(const bf16x8*)(w1p + j * 2048 + ks * 1024 + 512);
        }

    // 2. X(p+2) -> next regs (HBM; consumed next iter's staging)
    xp[PH ^ 1][0] = *(const float4*)(xsrc + (size_t)((p + 2) & 31) * 32);
    xp[PH ^ 1][1] = *(const float4*)(xsrc + (size_t)((p + 2) & 31) * 32 + 4);

    // 3. A fragments from buf[PH]: row = tr*32 + l31, k = ks*16 + h5*8 + i
    const int arow = tr * 32 + l31;
    bf16x8 axh[2], axm[2], axl[2];
#pragma unroll
    for (int ks = 0; ks < 2; ++ks) {
        const int ua = SWZ(arow, arow * 32 + ks * 16 + h5 * 8);
        axh[ks] = *(const bf16x8*)&Xh[PH][ua];
        axm[ks] = *(const bf16x8*)&Xm[PH][ua];
        axl[ks] = *(const bf16x8*)&Xl[PH][ua];
    }

    // 4. stage panel p+1 (data loaded LAST iter) -> buf[PH^1]
    {
        const float xs[8] = {xp[PH][0].x, xp[PH][0].y, xp[PH][0].z, xp[PH][0].w,
                             xp[PH][1].x, xp[PH][1].y, xp[PH][1].z, xp[PH][1].w};
        u16x8 sh, sm, sl;
#pragma unroll
        for (int q = 0; q < 8; ++q) {
            ushort h, m, l;
            split3r(xs[q], h, m, l);
            sh[q] = h; sm[q] = m; sl[q] = l;
        }
        const int us = SWZ(row, row * 32 + kc * 8);
        *(u16x8*)&Xh[PH ^ 1][us] = sh;
        *(u16x8*)&Xm[PH ^ 1][us] = sm;
        *(u16x8*)&Xl[PH ^ 1][us] = sl;
    }

    // 5. MFMA: per ks, logits 6-product + pred 3-product
#pragma unroll
    for (int ks = 0; ks < 2; ++ks) {
        accL = __builtin_amdgcn_mfma_f32_32x32x16_bf16(axh[ks], rwh[ks], accL, 0, 0, 0);
        accL = __builtin_amdgcn_mfma_f32_32x32x16_bf16(axm[ks], rwh[ks], accL, 0, 0, 0);
        accL = __builtin_amdgcn_mfma_f32_32x32x16_bf16(axh[ks], rwm[ks], accL, 0, 0, 0);
        accL = __builtin_amdgcn_mfma_f32_32x32x16_bf16(axl[ks], rwh[ks], accL, 0, 0, 0);
        accL = __builtin_amdgcn_mfma_f32_32x32x16_bf16(axh[ks], rwl[ks], accL, 0, 0, 0);
        accL = __builtin_amdgcn_mfma_f32_32x32x16_bf16(axm[ks], rwm[ks], accL, 0, 0, 0);
#pragma unroll
        for (int j = 0; j < 4; ++j) {
            accP[j] = __builtin_amdgcn_mfma_f32_32x32x16_bf16(axh[ks], bwh[ks][j], accP[j], 0, 0, 0);
            accP[j] = __builtin_amdgcn_mfma_f32_32x32x16_bf16(axm[ks], bwh[ks][j], accP[j], 0, 0, 0);
            accP[j] = __builtin_amdgcn_mfma_f32_32x32x16_bf16(axh[ks], bwl[ks][j], accP[j], 0, 0, 0);
        }
    }

    // 6. counted fence: drain LDS ops only; global loads stay in flight.
    asm volatile("s_waitcnt lgkmcnt(0)" ::: "memory");
    __builtin_amdgcn_s_barrier();
    __builtin_amdgcn_sched_barrier(0);
}

__global__ __launch_bounds__(256, 2) void fused_mfma(
    const float* __restrict__ X,
    const ushort* __restrict__ RWf, const ushort* __restrict__ W1f,
    const float* __restrict__ B1, const float* __restrict__ W2,
    const float* __restrict__ B2,
    float* __restrict__ logits, float* __restrict__ sel,
    float* __restrict__ wts, float* __restrict__ load_sum,
    float* __restrict__ ent_sum)
{
    __shared__ __align__(16) ushort Xh[2][2048], Xm[2][2048], Xl[2][2048];
    __shared__ float red[2][64];
    __shared__ float Lt[64][65];

    const int tid  = threadIdx.x;
    const int lane = tid & 63;
    const int w    = tid >> 6;           // 0..3
    const int tr   = w >> 1;             // token half (32 rows)
    const int tc   = w & 1;              // col half
    const int l31  = lane & 31;
    const int h5   = lane >> 5;
    const int tok0 = blockIdx.x * 64;

    const int row = tid >> 2;            // 0..63 (staging row)
    const int kc  = tid & 3;             // 8-float k-chunk

    f32x16 accL;
    f32x16 accP[4];
#pragma unroll
    for (int i = 0; i < 16; i++) accL[i] = 0.f;
#pragma unroll
    for (int j = 0; j < 4; j++)
#pragma unroll
        for (int i = 0; i < 16; i++) accP[j][i] = 0.f;

    const float* __restrict__ xsrc = X + (size_t)(tok0 + row) * HID + kc * 8;

    float4 xp[2][2];

    // ---- prologue: stage panel 0; prefetch X(1) ----
    {
        const float4 a0 = *(const float4*)(xsrc);
        const float4 a1 = *(const float4*)(xsrc + 4);
        const float xs[8] = {a0.x, a0.y, a0.z, a0.w, a1.x, a1.y, a1.z, a1.w};
        u16x8 sh, sm, sl;
#pragma unroll
        for (int q = 0; q < 8; ++q) {
            ushort h, m, l;
            split3r(xs[q], h, m, l);
            sh[q] = h; sm[q] = m; sl[q] = l;
        }
        const int us = SWZ(row, row * 32 + kc * 8);
        *(u16x8*)&Xh[0][us] = sh;
        *(u16x8*)&Xm[0][us] = sm;
        *(u16x8*)&Xl[0][us] = sl;
    }
    xp[0][0] = *(const float4*)(xsrc + 32);
    xp[0][1] = *(const float4*)(xsrc + 36);
    __syncthreads();

    for (int p = 0; p < 32; p += 2) {
        kstep<0>(p,     tr, tc, lane, l31, h5, row, kc, xsrc, RWf, W1f,
                 Xh, Xm, Xl, xp, accL, accP);
        kstep<1>(p + 1, tr, tc, lane, l31, h5, row, kc, xsrc, RWf, W1f,
                 Xh, Xm, Xl, xp, accL, accP);
    }

    // ---- logits epilogue (C/D 32x32: col=lane&31, row=(r&3)+8(r>>2)+4*h5) --
#pragma unroll
    for (int r = 0; r < 16; ++r) {
        const int orow = (r & 3) + 8 * (r >> 2) + 4 * h5;
        const int trow = tr * 32 + orow;
        logits[(size_t)(tok0 + trow) * NEXP + tc * 32 + l31] = accL[r];
        Lt[trow][tc * 32 + l31] = accL[r];
    }

    // ---- pred epilogue: bias+ReLU+w2 dot, 32-lane-half reduce ----
    float w2r[4], b1r[4];
#pragma unroll
    for (int j = 0; j < 4; ++j) {
        const int col = (tc * 4 + j) * 32 + l31;
        w2r[j] = W2[col];
        b1r[j] = B1[col];
    }
#pragma unroll
    for (int r = 0; r < 16; ++r) {
        float s = 0.f;
#pragma unroll
        for (int j = 0; j < 4; ++j) {
            const float hval = accP[j][r] + b1r[j];
            s = fmaf(w2r[j], fmaxf(hval, 0.f), s);
        }
        s += __shfl_xor(s, 1);
        s += __shfl_xor(s, 2);
        s += __shfl_xor(s, 4);
        s += __shfl_xor(s, 8);
        s += __shfl_xor(s, 16);
        if (l31 == 0)
            red[tc][tr * 32 + (r & 3) + 8 * (r >> 2) + 4 * h5] = s;
    }
    __syncthreads();

    // ---- route (verbatim proven math), wave 0, token = lane ----
    if (w == 0) {
        const int tok = tok0 + lane;

        float r[64];
#pragma unroll
        for (int e = 0; e < 64; e++) r[e] = Lt[lane][e];

        float v0 = -1e30f, v1 = -1e30f, v2 = -1e30f, v3 = -1e30f;
        int   i0 = 0, i1 = 0, i2 = 0, i3 = 0;
#pragma unroll
        for (int e = 0; e < 64; e++) {
            const float v = r[e];
            if (v > v3) {
                if (v > v2) {
                    if (v > v1) {
                        if (v > v0) { v3=v2;i3=i2; v2=v1;i2=i1; v1=v0;i1=i0; v0=v;i0=e; }
                        else        { v3=v2;i3=i2; v2=v1;i2=i1; v1=v;i1=e; }
                    } else          { v3=v2;i3=i2; v2=v;i2=e; }
                } else              { v3=v;i3=e; }
            }
        }

        const float s2 = red[0][lane] + red[1][lane] + B2[0];
        const bool k4 = (s2 > 0.f);

        float w0, w1v, w2v, w3v;
        int   s1i, s2i, s3i;
        if (k4) {
            const float e0 = expf(v0 - v0), e1 = expf(v1 - v0);
            const float e2 = expf(v2 - v0), e3 = expf(v3 - v0);
            const float inv4 = 1.f / (e0 + e1 + e2 + e3);
            w0 = e0 * inv4; w1v = e1 * inv4; w2v = e2 * inv4; w3v = e3 * inv4;
            s1i = i1; s2i = i2; s3i = i3;
        } else {
            w0 = 1.f; w1v = 0.f; w2v = 0.f; w3v = 0.f;
            s1i = 0; s2i = 0; s3i = 0;
        }
        {
            float4 sv = {(float)i0, (float)s1i, (float)s2i, (float)s3i};
            float4 wv = {w0, w1v, w2v, w3v};
            *(float4*)(sel + (size_t)tok * 4) = sv;
            *(float4*)(wts + (size_t)tok * 4) = wv;
        }

        const float mx = v0;
        float S = 0.f, pz = 0.f;
#pragma unroll
        for (int e = 0; e < 64; e++) {
            const float z = r[e] - mx;
            const float t = expf(z);
            S += t; pz = fmaf(t, z, pz);
            r[e] = t;
        }
        const float inv = 1.f / S;
        float ent = logf(S) - pz * inv;

        float myload = 0.f;
#pragma unroll
        for (int e = 0; e < 64; e++) {
            float s = r[e] * inv;
            s += __shfl_xor(s, 1);
            s += __shfl_xor(s, 2);
            s += __shfl_xor(s, 4);
            s += __shfl_xor(s, 8);
            s += __shfl_xor(s, 16);
            s += __shfl_xor(s, 32);
            if (lane == e) myload = s;
        }
        atomicAdd(&load_sum[lane], myload);

        ent += __shfl_xor(ent, 1);
        ent += __shfl_xor(ent, 2);
        ent += __shfl_xor(ent, 4);
        ent += __shfl_xor(ent, 8);
        ent += __shfl_xor(ent, 16);
        ent += __shfl_xor(ent, 32);
        if (lane == 0) atomicAdd(ent_sum, ent);
    }
}

__global__ void finalize_kernel(const float* __restrict__ load_sum,
                                const float* __restrict__ ent_sum,
                                float* __restrict__ out_scal)
{
    const int lane = threadIdx.x;
    const float le = load_sum[lane] * (1.f / (float)NTOK);
    float s = le;
#pragma unroll
    for (int o = 32; o >= 1; o >>= 1) s += __shfl_xor(s, o);
    const float mean = s * (1.f / 64.f);
    const float d = le - mean;
    float v = d * d;
#pragma unroll
    for (int o = 32; o >= 1; o >>= 1) v += __shfl_xor(v, o);
    if (lane == 0) {
        out_scal[0] = v * (1.f / 63.f);
        out_scal[1] = ent_sum[0] * (1.f / (float)NTOK);
    }
}

extern "C" void kernel_launch(void* const* d_in, const int* in_sizes, int n_in,
                              void* d_out, int out_size, void* d_ws, size_t ws_size,
                              hipStream_t stream) {
    const float* X  = (const float*)d_in[0];
    const float* RW = (const float*)d_in[1];
    const float* W1 = (const float*)d_in[2];
    const float* B1 = (const float*)d_in[3];
    const float* W2 = (const float*)d_in[4];
    const float* B2 = (const float*)d_in[5];

    float* out    = (float*)d_out;
    float* logits = out;
    float* sel    = out + (size_t)NTOK * NEXP;
    float* wts    = sel + (size_t)NTOK * 4;
    float* scal   = wts + (size_t)NTOK * 4;

    float* s2ws     = (float*)d_ws;                       // [32768] (unused in v13)
    float* load_sum = s2ws + NTOK;                        // [64]
    float* ent_sum  = load_sum + 64;                      // [1]
    ushort* W1f = (ushort*)(s2ws + NTOK + 256);           // 1 MB, 32x32 fragment-order
    ushort* RWf = W1f + (size_t)32 * 16384;               // 384 KB, 32x32 fragment-order

    hipMemsetAsync(load_sum, 0, 65 * sizeof(float), stream);

    prep_kernel<<<320, 256, 0, stream>>>(W1, RW, W1f, RWf);
    fused_mfma<<<NTOK / 64, 256, 0, stream>>>(X, RWf, W1f, B1, W2, B2,
                                              logits, sel, wts, load_sum, ent_sum);
    finalize_kernel<<<1, 64, 0, stream>>>(load_sum, ent_sum, scal);
}